// Round 12
// baseline (344.063 us; speedup 1.0000x reference)
//
#include <hip/hip_runtime.h>
#include <math.h>

// ---------- problem constants ----------
#define BB   8
#define NN   4096
#define CC   768
#define HH   12
#define DD   64
#define LL   64
#define BH   96          // BB*HH
#define MM_  32768       // BB*NN
#define KQKV 768
#define NQKV 2304
#define NTILES 24        // K / 32

typedef short bf16x8 __attribute__((ext_vector_type(8)));
typedef float f32x4  __attribute__((ext_vector_type(4)));
typedef float f32x16 __attribute__((ext_vector_type(16)));

union U4 { unsigned long long ll; unsigned short s[4]; };

__device__ __forceinline__ unsigned short f2bf(float f) {
  union { float f; unsigned u; } v; v.f = f;
  return (unsigned short)((v.u + 0x7FFFu + ((v.u >> 16) & 1u)) >> 16);
}
__device__ __forceinline__ float bf2f(unsigned short h) {
  union { unsigned u; float f; } v; v.u = ((unsigned)h) << 16;
  return v.f;
}
__device__ __forceinline__ f32x4 fzero4() {
  f32x4 z; z[0] = 0.f; z[1] = 0.f; z[2] = 0.f; z[3] = 0.f; return z;
}
__device__ __forceinline__ void gload_lds16(const void* g, void* l) {
  __builtin_amdgcn_global_load_lds(
      (const __attribute__((address_space(1))) void*)g,
      (__attribute__((address_space(3))) void*)l, 16, 0, 0);
}

// ---------- merged prep: fp32->bf16 convert + both weight transposes ----------
__global__ __launch_bounds__(256) void prep(
    const float* __restrict__ x, short* __restrict__ xb,
    const float* __restrict__ w_qkv, short* __restrict__ wqkvT,
    const float* __restrict__ w_proj, short* __restrict__ wprojT) {
  __shared__ float tile[32][33];
  int bid = blockIdx.x;
  if (bid < 24576) {
    int i = bid * 256 + threadIdx.x;
    float4 v = ((const float4*)x)[i];
    U4 p; p.s[0] = f2bf(v.x); p.s[1] = f2bf(v.y); p.s[2] = f2bf(v.z); p.s[3] = f2bf(v.w);
    ((unsigned long long*)xb)[i] = p.ll;
    return;
  }
  const float* in; short* out; int R, C, c0, r0;
  if (bid < 26304) {
    int j = bid - 24576;           // 72 x 24
    in = w_qkv; out = wqkvT; R = KQKV; C = NQKV;
    c0 = (j % 72) * 32; r0 = (j / 72) * 32;
  } else {
    int j = bid - 26304;           // 24 x 24
    in = w_proj; out = wprojT; R = CC; C = CC;
    c0 = (j % 24) * 32; r0 = (j / 24) * 32;
  }
  int tx = threadIdx.x & 31, ty = threadIdx.x >> 5;
  for (int i = ty; i < 32; i += 8)
    tile[i][tx] = in[(r0 + i) * C + c0 + tx];
  __syncthreads();
  for (int i = ty; i < 32; i += 8)
    out[(c0 + i) * R + r0 + tx] = (short)f2bf(tile[tx][i]);
}

// ---------- 128x128 bf16 MFMA GEMM, 3-slot ring, 3 blocks/CU, 32x32x16 MFMA ----------
// 256 threads = 4 waves (2Mx2N), per-wave 64x64 via 2x2 of 32x32 (8 MFMA/tile/wave,
// half the instruction count of 16x16x32 at identical LDS traffic).
// Swizzle f2(r)=((r>>1)&3)^((r>>3)&1), period 16 (32-row frags conflict-free).
// C/D layout (m74/m101-verified): col=lane&31, row=(reg&3)+8*(reg>>2)+4*(lane>>5).
template <int EPI>
__global__ __launch_bounds__(256, 3) void gemm128(
    const short* __restrict__ A, const short* __restrict__ Bw,
    short* __restrict__ o0, short* __restrict__ o1, short* __restrict__ o2,
    const float* __restrict__ bias, float* __restrict__ fout,
    short* __restrict__ Qlmb, short* __restrict__ Klmb,
    float* __restrict__ QlmF, float* __restrict__ KlmF) {
  __shared__ short L[24576];   // 48 KiB: slot s at s*16384 B (A 8KB | B 8KB)
  const int t = threadIdx.x;
  const int wave = t >> 6, lane = t & 63;
  const int wr = (wave >> 1) << 6, wc = (wave & 1) << 6;
  const int lane31 = lane & 31, g5 = lane >> 5;

  // XCD-contiguous mapping: XCD x owns tm range [x*32, x*32+32)
  const int x = (int)blockIdx.x & 7;
  const int local = (int)blockIdx.x >> 3;
  int tm, tn;
  if constexpr (EPI == 0) {
    const int phase = local / 288;          // 2 phases x (32 tm x 9 tn)
    const int r = local % 288;
    tm = x * 32 + r / 9;
    tn = phase * 9 + r % 9;
  } else {
    tm = x * 32 + local / 6;                // 32 tm x 6 tn, n-fastest
    tn = local % 6;
  }
  const int m0 = tm << 7;

  // staging: thread t stages 16B LDS slot t (and t+256) of each 8KB chunk.
  // slot s: row r=s>>2, pos p=s&3 holds element granule p^f2(r),
  // f2(r) = ((r>>1)&3) ^ ((r>>3)&1)  ->  csl = (p ^ f2) as elements
  const int csl = (((t & 3) ^ ((t >> 3) & 3) ^ ((t >> 5) & 1)) << 3);
  const short* pA0 = A  + (size_t)(m0 + (t >> 2)) * KQKV + csl;
  const short* pA1 = pA0 + 64 * KQKV;
  const short* pB0 = Bw + (size_t)(tn * 128 + (t >> 2)) * KQKV + csl;
  const short* pB1 = pB0 + 64 * KQKV;
  char* dA = (char*)L + t * 16;
  char* dB = (char*)L + 8192 + t * 16;

  // frag read: row = (wr|wc) + rf*32 + lane31; granule(ks) = ks*2 + g5;
  // byte = row*64 + ((granule ^ f2(row))<<4), f2(row) = ((lane>>1)&3)^((lane>>3)&1)
  const int f2l = ((lane >> 1) & 3) ^ ((lane >> 3) & 1);
  const int gs0 = (((0 + g5) ^ f2l) << 4);   // ks=0
  const int gs1 = (((2 + g5) ^ f2l) << 4);   // ks=1
  const int abase = (wr + lane31) * 64;           // + rf*2048 + slot*16384
  const int bbase = 8192 + (wc + lane31) * 64;    // + nf*2048

  f32x16 acc2[2][2];
#pragma unroll
  for (int i = 0; i < 2; ++i)
#pragma unroll
    for (int j = 0; j < 2; ++j)
#pragma unroll
      for (int q = 0; q < 16; ++q) acc2[i][j][q] = 0.f;

#pragma unroll
  for (int T = 0; T < 2; ++T) {
    gload_lds16(pA0 + T * 32, dA + T * 16384);
    gload_lds16(pA1 + T * 32, dA + T * 16384 + 4096);
    gload_lds16(pB0 + T * 32, dB + T * 16384);
    gload_lds16(pB1 + T * 32, dB + T * 16384 + 4096);
  }
  asm volatile("s_waitcnt vmcnt(4)" ::: "memory");
  __builtin_amdgcn_s_barrier();

  for (int T = 0; T < NTILES; ++T) {
    const int Ts = T + 2;
    if (Ts < NTILES) {
      const int sb = (Ts % 3) * 16384;
      gload_lds16(pA0 + Ts * 32, dA + sb);
      gload_lds16(pA1 + Ts * 32, dA + sb + 4096);
      gload_lds16(pB0 + Ts * 32, dB + sb);
      gload_lds16(pB1 + Ts * 32, dB + sb + 4096);
    }
    const char* Lb = (const char*)L + (T % 3) * 16384;
    bf16x8 a00 = *(const bf16x8*)(Lb + abase + gs0);
    bf16x8 a01 = *(const bf16x8*)(Lb + abase + gs1);
    bf16x8 a10 = *(const bf16x8*)(Lb + abase + 2048 + gs0);
    bf16x8 a11 = *(const bf16x8*)(Lb + abase + 2048 + gs1);
    bf16x8 b00 = *(const bf16x8*)(Lb + bbase + gs0);
    bf16x8 b01 = *(const bf16x8*)(Lb + bbase + gs1);
    bf16x8 b10 = *(const bf16x8*)(Lb + bbase + 2048 + gs0);
    bf16x8 b11 = *(const bf16x8*)(Lb + bbase + 2048 + gs1);
    acc2[0][0] = __builtin_amdgcn_mfma_f32_32x32x16_bf16(a00, b00, acc2[0][0], 0, 0, 0);
    acc2[0][1] = __builtin_amdgcn_mfma_f32_32x32x16_bf16(a00, b10, acc2[0][1], 0, 0, 0);
    acc2[1][0] = __builtin_amdgcn_mfma_f32_32x32x16_bf16(a10, b00, acc2[1][0], 0, 0, 0);
    acc2[1][1] = __builtin_amdgcn_mfma_f32_32x32x16_bf16(a10, b10, acc2[1][1], 0, 0, 0);
    acc2[0][0] = __builtin_amdgcn_mfma_f32_32x32x16_bf16(a01, b01, acc2[0][0], 0, 0, 0);
    acc2[0][1] = __builtin_amdgcn_mfma_f32_32x32x16_bf16(a01, b11, acc2[0][1], 0, 0, 0);
    acc2[1][0] = __builtin_amdgcn_mfma_f32_32x32x16_bf16(a11, b01, acc2[1][0], 0, 0, 0);
    acc2[1][1] = __builtin_amdgcn_mfma_f32_32x32x16_bf16(a11, b11, acc2[1][1], 0, 0, 0);
    if (T < NTILES - 2)       { asm volatile("s_waitcnt vmcnt(4)" ::: "memory"); }
    else if (T == NTILES - 2) { asm volatile("s_waitcnt vmcnt(0)" ::: "memory"); }
    __builtin_amdgcn_s_barrier();
  }

  // ================= epilogue =================
  if constexpr (EPI == 0) {
    const int cg0 = tn * 128;
    const int three = cg0 / 768;
    const int ccb = cg0 % 768;
    short* dst = (three == 0) ? o0 : (three == 1) ? o1 : o2;
    const float sc = (three == 0) ? 0.125f : 1.f;
    short* LS = (short*)L;              // [128][144] bf16
#pragma unroll
    for (int mf = 0; mf < 2; ++mf)
#pragma unroll
      for (int nf = 0; nf < 2; ++nf)
#pragma unroll
        for (int reg = 0; reg < 16; ++reg) {
          int r = wr + mf * 32 + (reg & 3) + 8 * (reg >> 2) + 4 * g5;
          int c = wc + nf * 32 + lane31;
          LS[r * 144 + c] = (short)f2bf(acc2[mf][nf][reg] * sc);
        }
    __syncthreads();
#pragma unroll
    for (int k = 0; k < 8; ++k) {
      int id = t + k * 256;
      int row = id >> 4, ch = id & 15;
      bf16x8 v = *(const bf16x8*)&LS[row * 144 + ch * 8];
      int c = ccb + ch * 8, h = c >> 6, d = c & 63;
      int r = m0 + row, bb = r >> 12, n = r & 4095;
      *(bf16x8*)&dst[((size_t)(bb * HH + h) * NN + n) * DD + d] = v;
    }
    if (three < 2) {
      int seg = t >> 7, col = t & 127;
      float ssum = 0.f;
#pragma unroll
      for (int j = 0; j < 64; ++j) ssum += bf2f((unsigned short)LS[(seg * 64 + j) * 144 + col]);
      ssum *= (1.f / 64.f);
      int l = ((tm & 31) << 1) + seg;
      int c = ccb + col, h = c >> 6, d = c & 63;
      int bh = (tm >> 5) * HH + h;
      int idx = bh * 4096 + l * 64 + d;
      if (three == 0) { QlmF[idx] = ssum; Qlmb[idx] = (short)f2bf(ssum); }
      else            { KlmF[idx] = ssum; Klmb[idx] = (short)f2bf(ssum); }
    }
  } else {
    float* LF = (float*)L;              // [64][136] f32 per pass
#pragma unroll
    for (int pass = 0; pass < 2; ++pass) {
      if ((wave >> 1) == pass) {
#pragma unroll
        for (int mf = 0; mf < 2; ++mf)
#pragma unroll
          for (int nf = 0; nf < 2; ++nf)
#pragma unroll
            for (int reg = 0; reg < 16; ++reg) {
              int r = mf * 32 + (reg & 3) + 8 * (reg >> 2) + 4 * g5;
              int c = wc + nf * 32 + lane31;
              LF[r * 136 + c] = acc2[mf][nf][reg];
            }
      }
      __syncthreads();
#pragma unroll
      for (int k = 0; k < 8; ++k) {
        int id = t + k * 256;
        int row = id >> 5, ch = id & 31;
        float4 v = *(const float4*)&LF[row * 136 + ch * 4];
        int R = m0 + pass * 64 + row;
        int c = tn * 128 + ch * 4;
        int bb = R >> 12, n = R & 4095, h = c >> 6, d = c & 63;
        float4 bi = *(const float4*)&bias[c];
        U4 r4;
        r4.ll = *(const unsigned long long*)&o2[((size_t)(bb * HH + h) * NN + n) * DD + d];
        v.x += bi.x + bf2f(r4.s[0]);
        v.y += bi.y + bf2f(r4.s[1]);
        v.z += bi.z + bf2f(r4.s[2]);
        v.w += bi.w + bf2f(r4.s[3]);
        *(float4*)&fout[(size_t)R * CC + c] = v;
      }
      __syncthreads();
    }
  }
}

// ---------- fused kernel3: per block 512 n-rows in 4 sub-chunks of 128 ----------
__global__ __launch_bounds__(256) void e12(
    const short* __restrict__ Kb, const short* __restrict__ Vb,
    const short* __restrict__ Qlmb,
    float* __restrict__ k3VTp, float* __restrict__ s3part) {
  int bh = blockIdx.y, chunk = blockIdx.x;
  __shared__ short Qlm[64 * 72];
  __shared__ short Plds[64 * 136];
  __shared__ short Vl[128 * 68];
  int t = threadIdx.x;
  for (int r = 0; r < 2; r++) {
    int e = t + r * 256;
    *(bf16x8*)&Qlm[(e >> 3) * 72 + (e & 7) * 8] = *(const bf16x8*)&Qlmb[bh * 4096 + e * 8];
  }
  int wave = t >> 6, lane = t & 63, lrow = lane & 15, g = lane >> 4, lk = g << 3;
  f32x4 o2[4];
  float cpl[4];
#pragma unroll
  for (int lf = 0; lf < 4; lf++) { o2[lf] = fzero4(); cpl[lf] = 0.f; }
  const int dloc = wave * 16 + lrow;

  for (int s = 0; s < 4; ++s) {
    int nb = chunk * 512 + s * 128;
    __syncthreads();
#pragma unroll
    for (int r = 0; r < 4; r++) {
      int id = t + r * 256;
      int n = id >> 3, c8 = id & 7;
      unsigned long long v1 = *(const unsigned long long*)&Vb[((size_t)bh * NN + nb + n) * DD + c8 * 8];
      unsigned long long v2 = *(const unsigned long long*)&Vb[((size_t)bh * NN + nb + n) * DD + c8 * 8 + 4];
      *(unsigned long long*)&Vl[n * 68 + c8 * 8] = v1;
      *(unsigned long long*)&Vl[n * 68 + c8 * 8 + 4] = v2;
    }
    int nw = nb + wave * 32;
    bf16x8 aK[2][2];
#pragma unroll
    for (int rf = 0; rf < 2; rf++)
#pragma unroll
      for (int ks = 0; ks < 2; ks++)
        aK[rf][ks] = *(const bf16x8*)&Kb[((size_t)bh * NN + nw + rf * 16 + lrow) * DD + ks * 32 + lk];
    f32x4 acc[2][4];
#pragma unroll
    for (int rf = 0; rf < 2; rf++)
#pragma unroll
      for (int lf = 0; lf < 4; lf++) acc[rf][lf] = fzero4();
#pragma unroll
    for (int ks = 0; ks < 2; ks++) {
      bf16x8 bq[4];
#pragma unroll
      for (int lf = 0; lf < 4; lf++)
        bq[lf] = *(const bf16x8*)&Qlm[(lf * 16 + lrow) * 72 + ks * 32 + lk];
#pragma unroll
      for (int rf = 0; rf < 2; rf++)
#pragma unroll
        for (int lf = 0; lf < 4; lf++)
          acc[rf][lf] = __builtin_amdgcn_mfma_f32_16x16x32_bf16(aK[rf][ks], bq[lf], acc[rf][lf], 0, 0, 0);
    }
#pragma unroll
    for (int lf = 0; lf < 4; lf++) {
      int l = lf * 16 + lrow;
#pragma unroll
      for (int rf = 0; rf < 2; rf++) {
        U4 p;
#pragma unroll
        for (int i = 0; i < 4; i++) {
          float e = expf(acc[rf][lf][i]);   // logits tiny: no max needed
          p.s[i] = f2bf(e); cpl[lf] += e;
        }
        *(unsigned long long*)&Plds[l * 136 + wave * 32 + rf * 16 + g * 4] = p.ll;
      }
    }
    __syncthreads();
#pragma unroll
    for (int ks = 0; ks < 4; ++ks) {
      bf16x8 a;
#pragma unroll
      for (int j = 0; j < 8; ++j) a[j] = Vl[(ks * 32 + lk + j) * 68 + dloc];
#pragma unroll
      for (int lf = 0; lf < 4; lf++) {
        bf16x8 b = *(const bf16x8*)&Plds[(lf * 16 + lrow) * 136 + ks * 32 + lk];
        o2[lf] = __builtin_amdgcn_mfma_f32_16x16x32_bf16(a, b, o2[lf], 0, 0, 0);
      }
    }
  }
#pragma unroll
  for (int lf = 0; lf < 4; lf++) {
    float cp = cpl[lf];
    cp += __shfl_xor(cp, 16);
    cp += __shfl_xor(cp, 32);
    if (lane < 16)
      s3part[((bh * 8 + chunk) * 4 + wave) * LL + lf * 16 + lane] = cp;
    int l = lf * 16 + lrow;
#pragma unroll
    for (int i = 0; i < 4; i++) {
      int dd = wave * 16 + g * 4 + i;
      k3VTp[((size_t)chunk * BH + bh) * 4096 + dd * 64 + l] = o2[lf][i];
    }
  }
}

// ---------- per-(b,h): kernel2 softmax + MFMA Newton-Schulz (bf16 hi/lo) ----------
__global__ __launch_bounds__(512) void newton_inv(
    const float* __restrict__ QlmF, const float* __restrict__ KlmF,
    const float* __restrict__ k3VTp, const float* __restrict__ s3part,
    short* __restrict__ MTws) {
  __shared__ float Cf[64 * 68];
  __shared__ short BUF[12 * 4608];
  __shared__ float red[64];
  __shared__ float denom_s;
  short* Crm_h  = BUF + 0 * 4608;  short* Crm_l  = BUF + 1 * 4608;
  short* Vrm_h  = BUF + 2 * 4608;  short* Vrm_l  = BUF + 3 * 4608;
  short* Vcm_h  = BUF + 4 * 4608;  short* Vcm_l  = BUF + 5 * 4608;
  short* T1rm_h = BUF + 6 * 4608;  short* T1rm_l = BUF + 7 * 4608;
  short* T1cm_h = BUF + 8 * 4608;  short* T1cm_l = BUF + 9 * 4608;
  short* T2cm_h = BUF + 10 * 4608; short* T2cm_l = BUF + 11 * 4608;
  float* A_ = (float*)BUF;          // phase-1 alias (dead before BUF reuse)
  float* B_ = A_ + 64 * 68;

  const int bh = blockIdx.x, t = threadIdx.x;
  const int row = t >> 3, c0 = (t & 7) << 3;
  const int wv = t >> 6, lane = t & 63, lrow = lane & 15, g = lane >> 4;
  const int rw = (wv >> 1) * 16, cw = (wv & 1) * 32;

#pragma unroll
  for (int i = 0; i < 8; i++) {
    int e = t * 8 + i;
    A_[(e >> 6) * 68 + (e & 63)] = QlmF[bh * 4096 + e];
    B_[(e >> 6) * 68 + (e & 63)] = KlmF[bh * 4096 + e];
  }
  __syncthreads();
  {  // S2 = Qlm @ Klm^T ; row softmax -> Cf
    float4 ar[16];
#pragma unroll
    for (int q = 0; q < 16; q++) ar[q] = *(const float4*)&A_[row * 68 + q * 4];
    float o[8];
#pragma unroll
    for (int mm = 0; mm < 8; mm++) {
      const float4* br = (const float4*)&B_[(c0 + mm) * 68];
      float s = 0.f;
      for (int q = 0; q < 16; q++) {
        float4 b4 = br[q];
        s += ar[q].x * b4.x + ar[q].y * b4.y + ar[q].z * b4.z + ar[q].w * b4.w;
      }
      o[mm] = s;
    }
    float mx = o[0];
#pragma unroll
    for (int mm = 1; mm < 8; mm++) mx = fmaxf(mx, o[mm]);
    mx = fmaxf(mx, __shfl_xor(mx, 1));
    mx = fmaxf(mx, __shfl_xor(mx, 2));
    mx = fmaxf(mx, __shfl_xor(mx, 4));
    float ss = 0.f;
#pragma unroll
    for (int mm = 0; mm < 8; mm++) { o[mm] = expf(o[mm] - mx); ss += o[mm]; }
    ss += __shfl_xor(ss, 1); ss += __shfl_xor(ss, 2); ss += __shfl_xor(ss, 4);
    float r = 1.f / ss;
#pragma unroll
    for (int mm = 0; mm < 8; mm++) Cf[row * 68 + c0 + mm] = o[mm] * r;
  }
  __syncthreads();
  if (t < 64) {
    float s = 0.f;
    for (int l2 = 0; l2 < 64; l2++) s += Cf[l2 * 68 + t];
    red[t] = s;
  }
  __syncthreads();
  if (t == 0) {
    float m = red[0];
    for (int i = 1; i < 64; i++) m = fmaxf(m, red[i]);
    denom_s = m;
  }
  __syncthreads();
  {  // init: C hi/lo (rm); V0 = C^T/denom hi/lo (rm + cm)
    float rdn = 1.f / denom_s;
#pragma unroll
    for (int i = 0; i < 8; i++) {
      int e = t * 8 + i, r = e >> 6, c = e & 63;
      float cv = Cf[r * 68 + c];
      unsigned short chh = f2bf(cv);
      Crm_h[r * 72 + c] = (short)chh;
      Crm_l[r * 72 + c] = (short)f2bf(cv - bf2f(chh));
      float vv = Cf[c * 68 + r] * rdn;
      unsigned short vh = f2bf(vv);
      unsigned short vl = f2bf(vv - bf2f(vh));
      Vrm_h[r * 72 + c] = (short)vh; Vrm_l[r * 72 + c] = (short)vl;
      Vcm_h[c * 72 + r] = (short)vh; Vcm_l[c * 72 + r] = (short)vl;
    }
  }
  __syncthreads();

  f32x4 acc[2];
  auto mfmm = [&](const short* Xh, const short* Xl, const short* Yh, const short* Yl) {
    acc[0] = fzero4(); acc[1] = fzero4();
#pragma unroll
    for (int ks = 0; ks < 2; ++ks) {
      bf16x8 ah = *(const bf16x8*)&Xh[(rw + lrow) * 72 + ks * 32 + g * 8];
      bf16x8 al = *(const bf16x8*)&Xl[(rw + lrow) * 72 + ks * 32 + g * 8];
#pragma unroll
      for (int cf = 0; cf < 2; ++cf) {
        const int c = cw + cf * 16 + lrow;
        bf16x8 bhv = *(const bf16x8*)&Yh[c * 72 + ks * 32 + g * 8];
        bf16x8 blv = *(const bf16x8*)&Yl[c * 72 + ks * 32 + g * 8];
        acc[cf] = __builtin_amdgcn_mfma_f32_16x16x32_bf16(ah, bhv, acc[cf], 0, 0, 0);
        acc[cf] = __builtin_amdgcn_mfma_f32_16x16x32_bf16(ah, blv, acc[cf], 0, 0, 0);
        acc[cf] = __builtin_amdgcn_mfma_f32_16x16x32_bf16(al, bhv, acc[cf], 0, 0, 0);
      }
    }
  };
  auto storeRM = [&](short* H, short* Lo) {
#pragma unroll
    for (int cf = 0; cf < 2; ++cf)
#pragma unroll
      for (int i = 0; i < 4; ++i) {
        float z = acc[cf][i];
        unsigned short h = f2bf(z);
        int r = rw + g * 4 + i, c = cw + cf * 16 + lrow;
        H[r * 72 + c] = (short)h;
        Lo[r * 72 + c] = (short)f2bf(z - bf2f(h));
      }
  };
  auto storeCM = [&](short* H, short* Lo) {
#pragma unroll
    for (int cf = 0; cf < 2; ++cf) {
      U4 ph, pl;
#pragma unroll
      for (int i = 0; i < 4; ++i) {
        float z = acc[cf][i];
        unsigned short h = f2bf(z);
        ph.s[i] = h; pl.s[i] = f2bf(z - bf2f(h));
      }
      int c = cw + cf * 16 + lrow;
      *(unsigned long long*)&H[c * 72 + rw + g * 4] = ph.ll;
      *(unsigned long long*)&Lo[c * 72 + rw + g * 4] = pl.ll;
    }
  };

  float t1v[2][4];
  for (int it = 0; it < 6; ++it) {
    mfmm(Crm_h, Crm_l, Vcm_h, Vcm_l);          // T1 = C @ V
    __syncthreads();
    storeRM(T1rm_h, T1rm_l); storeCM(T1cm_h, T1cm_l);
    __syncthreads();
    mfmm(T1rm_h, T1rm_l, T1cm_h, T1cm_l);      // T1 @ T1
#pragma unroll
    for (int cf = 0; cf < 2; ++cf)
#pragma unroll
      for (int i = 0; i < 4; ++i) {
        int r = rw + g * 4 + i, c = cw + cf * 16 + lrow;
        t1v[cf][i] = bf2f((unsigned short)T1rm_h[r * 72 + c]) +
                     bf2f((unsigned short)T1rm_l[r * 72 + c]);
        acc[cf][i] = 7.f * t1v[cf][i] - acc[cf][i];
      }
    __syncthreads();
    storeCM(T2cm_h, T2cm_l);                   // T2 = 7*T1 - T1@T1
    __syncthreads();
    mfmm(T1rm_h, T1rm_l, T2cm_h, T2cm_l);      // T1 @ T2
#pragma unroll
    for (int cf = 0; cf < 2; ++cf)
#pragma unroll
      for (int i = 0; i < 4; ++i)
        acc[cf][i] = 15.f * t1v[cf][i] - acc[cf][i];
    __syncthreads();
    storeCM(T2cm_h, T2cm_l);                   // T3 overwrites T2 (post-barrier)
    __syncthreads();
    mfmm(Vrm_h, Vrm_l, T2cm_h, T2cm_l);        // V @ T3
#pragma unroll
    for (int cf = 0; cf < 2; ++cf)
#pragma unroll
      for (int i = 0; i < 4; ++i) {
        int r = rw + g * 4 + i, c = cw + cf * 16 + lrow;
        float v0 = bf2f((unsigned short)Vrm_h[r * 72 + c]) +
                   bf2f((unsigned short)Vrm_l[r * 72 + c]);
        acc[cf][i] = 0.25f * (13.f * v0 - acc[cf][i]);
      }
    __syncthreads();
    storeRM(Vrm_h, Vrm_l); storeCM(Vcm_h, Vcm_l);
    __syncthreads();
  }

  if (t < 64) {
    float s = 0.f;
    for (int i2 = 0; i2 < 32; i2++) s += s3part[(bh * 32 + i2) * LL + t];
    red[t] = 1.f / s;
  }
  __syncthreads();
#pragma unroll
  for (int i = 0; i < 8; i++) {
    int e = t * 8 + i, d = e >> 6, m = e & 63;
    float s = 0.f;
#pragma unroll
    for (int c = 0; c < 8; c++) s += k3VTp[((size_t)c * BH + bh) * 4096 + e];
    s *= red[m];
    unsigned short h = f2bf(s);
    T1rm_h[d * 72 + m] = (short)h;
    T1rm_l[d * 72 + m] = (short)f2bf(s - bf2f(h));
  }
  __syncthreads();
  mfmm(T1rm_h, T1rm_l, Vrm_h, Vrm_l);
#pragma unroll
  for (int cf = 0; cf < 2; ++cf)
#pragma unroll
    for (int i = 0; i < 4; ++i)
      MTws[bh * 4096 + (rw + g * 4 + i) * 64 + cw + cf * 16 + lrow] =
          (short)f2bf(acc[cf][i]);
}

// ---------- kernel1 softmax + @M  -> SV (in [B,N,C] bf16) ----------
__global__ __launch_bounds__(256) void pass2(
    const short* __restrict__ Qb, const short* __restrict__ Klmb,
    const short* __restrict__ MTws, short* __restrict__ SVb) {
  int bh = blockIdx.y, n0 = blockIdx.x * 128;
  int bb = bh / HH, hh = bh % HH;
  __shared__ short Klm[64 * 72];
  __shared__ short Mt[64 * 72];
  __shared__ short Pl[128 * 72];
  int t = threadIdx.x;
  for (int r = 0; r < 2; r++) {
    int e = t + r * 256;
    *(bf16x8*)&Klm[(e >> 3) * 72 + (e & 7) * 8] = *(const bf16x8*)&Klmb[bh * 4096 + e * 8];
    *(bf16x8*)&Mt[(e >> 3) * 72 + (e & 7) * 8]  = *(const bf16x8*)&MTws[bh * 4096 + e * 8];
  }
  __syncthreads();
  int wave = t >> 6, lane = t & 63, lrow = lane & 15, lk = (lane >> 4) << 3;
  int nw = wave * 32;
  bf16x8 aQ[2][2];
#pragma unroll
  for (int rf = 0; rf < 2; rf++)
#pragma unroll
    for (int ks = 0; ks < 2; ks++)
      aQ[rf][ks] = *(const bf16x8*)&Qb[((size_t)bh * NN + n0 + nw + rf * 16 + lrow) * DD + ks * 32 + lk];
  f32x4 s[2][4];
#pragma unroll
  for (int rf = 0; rf < 2; rf++)
#pragma unroll
    for (int jf = 0; jf < 4; jf++) s[rf][jf] = fzero4();
#pragma unroll
  for (int ks = 0; ks < 2; ks++) {
    bf16x8 bk[4];
#pragma unroll
    for (int jf = 0; jf < 4; jf++)
      bk[jf] = *(const bf16x8*)&Klm[(jf * 16 + lrow) * 72 + ks * 32 + lk];
#pragma unroll
    for (int rf = 0; rf < 2; rf++)
#pragma unroll
      for (int jf = 0; jf < 4; jf++)
        s[rf][jf] = __builtin_amdgcn_mfma_f32_16x16x32_bf16(aQ[rf][ks], bk[jf], s[rf][jf], 0, 0, 0);
  }
#pragma unroll
  for (int rf = 0; rf < 2; rf++)
#pragma unroll
    for (int i = 0; i < 4; i++) {
      float v0 = s[rf][0][i], v1 = s[rf][1][i], v2 = s[rf][2][i], v3 = s[rf][3][i];
      float mx = fmaxf(fmaxf(v0, v1), fmaxf(v2, v3));
      mx = fmaxf(mx, __shfl_xor(mx, 1));
      mx = fmaxf(mx, __shfl_xor(mx, 2));
      mx = fmaxf(mx, __shfl_xor(mx, 4));
      mx = fmaxf(mx, __shfl_xor(mx, 8));
      v0 = expf(v0 - mx); v1 = expf(v1 - mx); v2 = expf(v2 - mx); v3 = expf(v3 - mx);
      float ss = v0 + v1 + v2 + v3;
      ss += __shfl_xor(ss, 1); ss += __shfl_xor(ss, 2);
      ss += __shfl_xor(ss, 4); ss += __shfl_xor(ss, 8);
      float rr = 1.f / ss;
      int n = nw + rf * 16 + ((lane >> 4) << 2) + i;
      Pl[n * 72 + 0  + lrow] = (short)f2bf(v0 * rr);
      Pl[n * 72 + 16 + lrow] = (short)f2bf(v1 * rr);
      Pl[n * 72 + 32 + lrow] = (short)f2bf(v2 * rr);
      Pl[n * 72 + 48 + lrow] = (short)f2bf(v3 * rr);
    }
  __syncthreads();
  f32x4 o[2][4];
#pragma unroll
  for (int rf = 0; rf < 2; rf++)
#pragma unroll
    for (int df = 0; df < 4; df++) o[rf][df] = fzero4();
#pragma unroll
  for (int ks = 0; ks < 2; ks++) {
    bf16x8 aP[2];
#pragma unroll
    for (int rf = 0; rf < 2; rf++)
      aP[rf] = *(const bf16x8*)&Pl[(nw + rf * 16 + lrow) * 72 + ks * 32 + lk];
    bf16x8 bm[4];
#pragma unroll
    for (int df = 0; df < 4; df++)
      bm[df] = *(const bf16x8*)&Mt[(df * 16 + lrow) * 72 + ks * 32 + lk];
#pragma unroll
    for (int rf = 0; rf < 2; rf++)
#pragma unroll
      for (int df = 0; df < 4; df++)
        o[rf][df] = __builtin_amdgcn_mfma_f32_16x16x32_bf16(aP[rf], bm[df], o[rf][df], 0, 0, 0);
  }
#pragma unroll
  for (int rf = 0; rf < 2; rf++)
#pragma unroll
    for (int df = 0; df < 4; df++)
#pragma unroll
      for (int i = 0; i < 4; i++) {
        int n = n0 + nw + rf * 16 + ((lane >> 4) << 2) + i;
        SVb[((size_t)bb * NN + n) * CC + hh * 64 + df * 16 + lrow] = (short)f2bf(o[rf][df][i]);
      }
}

extern "C" void kernel_launch(void* const* d_in, const int* in_sizes, int n_in,
                              void* d_out, int out_size, void* d_ws, size_t ws_size,
                              hipStream_t stream) {
  const float* x      = (const float*)d_in[0];
  const float* w_qkv  = (const float*)d_in[1];
  const float* w_proj = (const float*)d_in[2];
  const float* b_proj = (const float*)d_in[3];
  float* out = (float*)d_out;

  char* p = (char*)d_ws;
  auto alloc = [&](size_t bytes) -> char* {
    char* r = p; p += (bytes + 255) & ~(size_t)255; return r;
  };
  short* xb     = (short*)alloc((size_t)MM_ * KQKV * 2);
  short* wqkvT  = (short*)alloc((size_t)NQKV * KQKV * 2);
  short* wprojT = (short*)alloc((size_t)CC * CC * 2);
  short* Qb     = (short*)alloc((size_t)BH * NN * DD * 2);
  short* Kb     = (short*)alloc((size_t)BH * NN * DD * 2);
  short* Vb     = (short*)alloc((size_t)BH * NN * DD * 2);
  short* Qlmb   = (short*)alloc((size_t)BH * LL * DD * 2);
  short* Klmb   = (short*)alloc((size_t)BH * LL * DD * 2);
  float* QlmF   = (float*)alloc((size_t)BH * LL * DD * 4);
  float* KlmF   = (float*)alloc((size_t)BH * LL * DD * 4);
  float* s3part = (float*)alloc((size_t)BH * 32 * LL * 4);
  float* k3VTp  = (float*)alloc((size_t)8 * BH * DD * LL * 4);
  short* MTws   = (short*)alloc((size_t)BH * DD * LL * 2);
  short* SVb    = (short*)alloc((size_t)MM_ * CC * 2);

  prep<<<26880, 256, 0, stream>>>(x, xb, w_qkv, wqkvT, w_proj, wprojT);
  gemm128<0><<<dim3((MM_ / 128) * (NQKV / 128)), 256, 0, stream>>>(
      xb, wqkvT, Qb, Kb, Vb, nullptr, nullptr, Qlmb, Klmb, QlmF, KlmF);
  e12<<<dim3(8, BH), 256, 0, stream>>>(Kb, Vb, Qlmb, k3VTp, s3part);
  newton_inv<<<BH, 512, 0, stream>>>(QlmF, KlmF, k3VTp, s3part, MTws);
  pass2<<<dim3(NN / 128, BH), 256, 0, stream>>>(Qb, Klmb, MTws, SVb);
  gemm128<1><<<dim3((MM_ / 128) * (CC / 128)), 256, 0, stream>>>(
      SVb, wprojT, nullptr, nullptr, Vb, b_proj, out,
      nullptr, nullptr, nullptr, nullptr);
}

// Round 14
// 333.086 us; speedup vs baseline: 1.0330x; 1.0330x over previous
//
#include <hip/hip_runtime.h>
#include <math.h>

// ---------- problem constants ----------
#define BB   8
#define NN   4096
#define CC   768
#define HH   12
#define DD   64
#define LL   64
#define BH   96          // BB*HH
#define MM_  32768       // BB*NN
#define KQKV 768
#define NQKV 2304
#define NTILES 24        // K / 32

typedef short bf16x8 __attribute__((ext_vector_type(8)));
typedef float f32x4  __attribute__((ext_vector_type(4)));

union U4 { unsigned long long ll; unsigned short s[4]; };

__device__ __forceinline__ unsigned short f2bf(float f) {
  union { float f; unsigned u; } v; v.f = f;
  return (unsigned short)((v.u + 0x7FFFu + ((v.u >> 16) & 1u)) >> 16);
}
__device__ __forceinline__ float bf2f(unsigned short h) {
  union { unsigned u; float f; } v; v.u = ((unsigned)h) << 16;
  return v.f;
}
__device__ __forceinline__ f32x4 fzero4() {
  f32x4 z; z[0] = 0.f; z[1] = 0.f; z[2] = 0.f; z[3] = 0.f; return z;
}
__device__ __forceinline__ void gload_lds16(const void* g, void* l) {
  __builtin_amdgcn_global_load_lds(
      (const __attribute__((address_space(1))) void*)g,
      (__attribute__((address_space(3))) void*)l, 16, 0, 0);
}

// ---------- merged prep: fp32->bf16 convert + both weight transposes ----------
__global__ __launch_bounds__(256) void prep(
    const float* __restrict__ x, short* __restrict__ xb,
    const float* __restrict__ w_qkv, short* __restrict__ wqkvT,
    const float* __restrict__ w_proj, short* __restrict__ wprojT) {
  __shared__ float tile[32][33];
  int bid = blockIdx.x;
  if (bid < 24576) {
    int i = bid * 256 + threadIdx.x;
    float4 v = ((const float4*)x)[i];
    U4 p; p.s[0] = f2bf(v.x); p.s[1] = f2bf(v.y); p.s[2] = f2bf(v.z); p.s[3] = f2bf(v.w);
    ((unsigned long long*)xb)[i] = p.ll;
    return;
  }
  const float* in; short* out; int R, C, c0, r0;
  if (bid < 26304) {
    int j = bid - 24576;           // 72 x 24
    in = w_qkv; out = wqkvT; R = KQKV; C = NQKV;
    c0 = (j % 72) * 32; r0 = (j / 72) * 32;
  } else {
    int j = bid - 26304;           // 24 x 24
    in = w_proj; out = wprojT; R = CC; C = CC;
    c0 = (j % 24) * 32; r0 = (j / 24) * 32;
  }
  int tx = threadIdx.x & 31, ty = threadIdx.x >> 5;
  for (int i = ty; i < 32; i += 8)
    tile[i][tx] = in[(r0 + i) * C + c0 + tx];
  __syncthreads();
  for (int i = ty; i < 32; i += 8)
    out[(c0 + i) * R + r0 + tx] = (short)f2bf(tile[tx][i]);
}

// ---------- 128x128 bf16 MFMA GEMM, 3-slot ring, 3 blocks/CU (round-9 config) ----------
template <int EPI>
__global__ __launch_bounds__(256, 3) void gemm128(
    const short* __restrict__ A, const short* __restrict__ Bw,
    short* __restrict__ o0, short* __restrict__ o1, short* __restrict__ o2,
    const float* __restrict__ bias, float* __restrict__ fout,
    short* __restrict__ Qlmb, short* __restrict__ Klmb,
    float* __restrict__ QlmF, float* __restrict__ KlmF) {
  __shared__ short L[24576];   // 48 KiB: slot s at s*16384 B (A 8KB | B 8KB)
  const int t = threadIdx.x;
  const int wave = t >> 6, lane = t & 63;
  const int wr = (wave >> 1) << 6, wc = (wave & 1) << 6;
  const int lrow = lane & 15, g = lane >> 4;

  // XCD-contiguous mapping: XCD x owns tm range [x*32, x*32+32)
  const int x = (int)blockIdx.x & 7;
  const int local = (int)blockIdx.x >> 3;
  int tm, tn;
  if constexpr (EPI == 0) {
    const int phase = local / 288;          // 2 phases x (32 tm x 9 tn)
    const int r = local % 288;
    tm = x * 32 + r / 9;
    tn = phase * 9 + r % 9;
  } else {
    tm = x * 32 + local / 6;                // 32 tm x 6 tn, n-fastest
    tn = local % 6;
  }
  const int m0 = tm << 7;

  const int csl = (((t & 3) ^ ((t >> 3) & 3)) << 3);
  const short* pA0 = A  + (size_t)(m0 + (t >> 2)) * KQKV + csl;
  const short* pA1 = pA0 + 64 * KQKV;
  const short* pB0 = Bw + (size_t)(tn * 128 + (t >> 2)) * KQKV + csl;
  const short* pB1 = pB0 + 64 * KQKV;
  char* dA = (char*)L + t * 16;
  char* dB = (char*)L + 8192 + t * 16;

  const int swz = ((g ^ ((lrow >> 1) & 3)) << 4);
  const int aoff = (wr + lrow) * 64 + swz;
  const int boff = 8192 + (wc + lrow) * 64 + swz;

  f32x4 acc[4][4];
#pragma unroll
  for (int i = 0; i < 4; ++i)
#pragma unroll
    for (int j = 0; j < 4; ++j) acc[i][j] = fzero4();

#pragma unroll
  for (int T = 0; T < 2; ++T) {
    gload_lds16(pA0 + T * 32, dA + T * 16384);
    gload_lds16(pA1 + T * 32, dA + T * 16384 + 4096);
    gload_lds16(pB0 + T * 32, dB + T * 16384);
    gload_lds16(pB1 + T * 32, dB + T * 16384 + 4096);
  }
  asm volatile("s_waitcnt vmcnt(4)" ::: "memory");
  __builtin_amdgcn_s_barrier();

  for (int T = 0; T < NTILES; ++T) {
    const int Ts = T + 2;
    if (Ts < NTILES) {
      const int sb = (Ts % 3) * 16384;
      gload_lds16(pA0 + Ts * 32, dA + sb);
      gload_lds16(pA1 + Ts * 32, dA + sb + 4096);
      gload_lds16(pB0 + Ts * 32, dB + sb);
      gload_lds16(pB1 + Ts * 32, dB + sb + 4096);
    }
    const char* Lb = (const char*)L + (T % 3) * 16384;
    bf16x8 a[4], b[4];
#pragma unroll
    for (int nf = 0; nf < 4; ++nf) b[nf] = *(const bf16x8*)(Lb + boff + nf * 1024);
#pragma unroll
    for (int rf = 0; rf < 4; ++rf) a[rf] = *(const bf16x8*)(Lb + aoff + rf * 1024);
#pragma unroll
    for (int rf = 0; rf < 4; ++rf)
#pragma unroll
      for (int nf = 0; nf < 4; ++nf)
        acc[rf][nf] = __builtin_amdgcn_mfma_f32_16x16x32_bf16(a[rf], b[nf], acc[rf][nf], 0, 0, 0);
    if (T < NTILES - 2)       { asm volatile("s_waitcnt vmcnt(4)" ::: "memory"); }
    else if (T == NTILES - 2) { asm volatile("s_waitcnt vmcnt(0)" ::: "memory"); }
    __builtin_amdgcn_s_barrier();
  }

  // ================= epilogue =================
  if constexpr (EPI == 0) {
    const int cg0 = tn * 128;
    const int three = cg0 / 768;
    const int ccb = cg0 % 768;
    short* dst = (three == 0) ? o0 : (three == 1) ? o1 : o2;
    const float sc = (three == 0) ? 0.125f : 1.f;
    short* LS = (short*)L;              // [128][144] bf16
#pragma unroll
    for (int rf = 0; rf < 4; ++rf)
#pragma unroll
      for (int nf = 0; nf < 4; ++nf)
#pragma unroll
        for (int i = 0; i < 4; ++i)
          LS[(wr + rf * 16 + g * 4 + i) * 144 + wc + nf * 16 + lrow] =
              (short)f2bf(acc[rf][nf][i] * sc);
    __syncthreads();
#pragma unroll
    for (int k = 0; k < 8; ++k) {
      int id = t + k * 256;
      int row = id >> 4, ch = id & 15;
      bf16x8 v = *(const bf16x8*)&LS[row * 144 + ch * 8];
      int c = ccb + ch * 8, h = c >> 6, d = c & 63;
      int r = m0 + row, bb = r >> 12, n = r & 4095;
      *(bf16x8*)&dst[((size_t)(bb * HH + h) * NN + n) * DD + d] = v;
    }
    if (three < 2) {
      int seg = t >> 7, col = t & 127;
      float ssum = 0.f;
#pragma unroll
      for (int j = 0; j < 64; ++j) ssum += bf2f((unsigned short)LS[(seg * 64 + j) * 144 + col]);
      ssum *= (1.f / 64.f);
      int l = ((tm & 31) << 1) + seg;
      int c = ccb + col, h = c >> 6, d = c & 63;
      int bh = (tm >> 5) * HH + h;
      int idx = bh * 4096 + l * 64 + d;
      if (three == 0) { QlmF[idx] = ssum; Qlmb[idx] = (short)f2bf(ssum); }
      else            { KlmF[idx] = ssum; Klmb[idx] = (short)f2bf(ssum); }
    }
  } else {
    float* LF = (float*)L;              // [64][136] f32 per pass
#pragma unroll
    for (int pass = 0; pass < 2; ++pass) {
      if ((wave >> 1) == pass) {
#pragma unroll
        for (int rf = 0; rf < 4; ++rf)
#pragma unroll
          for (int nf = 0; nf < 4; ++nf)
#pragma unroll
            for (int i = 0; i < 4; ++i)
              LF[(rf * 16 + g * 4 + i) * 136 + wc + nf * 16 + lrow] = acc[rf][nf][i];
      }
      __syncthreads();
#pragma unroll
      for (int k = 0; k < 8; ++k) {
        int id = t + k * 256;
        int row = id >> 5, ch = id & 31;
        float4 v = *(const float4*)&LF[row * 136 + ch * 4];
        int R = m0 + pass * 64 + row;
        int c = tn * 128 + ch * 4;
        int bb = R >> 12, n = R & 4095, h = c >> 6, d = c & 63;
        float4 bi = *(const float4*)&bias[c];
        U4 r4;
        r4.ll = *(const unsigned long long*)&o2[((size_t)(bb * HH + h) * NN + n) * DD + d];
        v.x += bi.x + bf2f(r4.s[0]);
        v.y += bi.y + bf2f(r4.s[1]);
        v.z += bi.z + bf2f(r4.s[2]);
        v.w += bi.w + bf2f(r4.s[3]);
        *(float4*)&fout[(size_t)R * CC + c] = v;
      }
      __syncthreads();
    }
  }
}

// ---------- fused kernel3: per block 512 n-rows in 4 sub-chunks of 128 ----------
__global__ __launch_bounds__(256) void e12(
    const short* __restrict__ Kb, const short* __restrict__ Vb,
    const short* __restrict__ Qlmb,
    float* __restrict__ k3VTp, float* __restrict__ s3part) {
  int bh = blockIdx.y, chunk = blockIdx.x;
  __shared__ short Qlm[64 * 72];
  __shared__ short Plds[64 * 136];
  __shared__ short Vl[128 * 68];
  int t = threadIdx.x;
  for (int r = 0; r < 2; r++) {
    int e = t + r * 256;
    *(bf16x8*)&Qlm[(e >> 3) * 72 + (e & 7) * 8] = *(const bf16x8*)&Qlmb[bh * 4096 + e * 8];
  }
  int wave = t >> 6, lane = t & 63, lrow = lane & 15, g = lane >> 4, lk = g << 3;
  f32x4 o2[4];
  float cpl[4];
#pragma unroll
  for (int lf = 0; lf < 4; lf++) { o2[lf] = fzero4(); cpl[lf] = 0.f; }
  const int dloc = wave * 16 + lrow;

  for (int s = 0; s < 4; ++s) {
    int nb = chunk * 512 + s * 128;
    __syncthreads();
#pragma unroll
    for (int r = 0; r < 4; r++) {
      int id = t + r * 256;
      int n = id >> 3, c8 = id & 7;
      unsigned long long v1 = *(const unsigned long long*)&Vb[((size_t)bh * NN + nb + n) * DD + c8 * 8];
      unsigned long long v2 = *(const unsigned long long*)&Vb[((size_t)bh * NN + nb + n) * DD + c8 * 8 + 4];
      *(unsigned long long*)&Vl[n * 68 + c8 * 8] = v1;
      *(unsigned long long*)&Vl[n * 68 + c8 * 8 + 4] = v2;
    }
    int nw = nb + wave * 32;
    bf16x8 aK[2][2];
#pragma unroll
    for (int rf = 0; rf < 2; rf++)
#pragma unroll
      for (int ks = 0; ks < 2; ks++)
        aK[rf][ks] = *(const bf16x8*)&Kb[((size_t)bh * NN + nw + rf * 16 + lrow) * DD + ks * 32 + lk];
    f32x4 acc[2][4];
#pragma unroll
    for (int rf = 0; rf < 2; rf++)
#pragma unroll
      for (int lf = 0; lf < 4; lf++) acc[rf][lf] = fzero4();
#pragma unroll
    for (int ks = 0; ks < 2; ks++) {
      bf16x8 bq[4];
#pragma unroll
      for (int lf = 0; lf < 4; lf++)
        bq[lf] = *(const bf16x8*)&Qlm[(lf * 16 + lrow) * 72 + ks * 32 + lk];
#pragma unroll
      for (int rf = 0; rf < 2; rf++)
#pragma unroll
        for (int lf = 0; lf < 4; lf++)
          acc[rf][lf] = __builtin_amdgcn_mfma_f32_16x16x32_bf16(aK[rf][ks], bq[lf], acc[rf][lf], 0, 0, 0);
    }
#pragma unroll
    for (int lf = 0; lf < 4; lf++) {
      int l = lf * 16 + lrow;
#pragma unroll
      for (int rf = 0; rf < 2; rf++) {
        U4 p;
#pragma unroll
        for (int i = 0; i < 4; i++) {
          float e = expf(acc[rf][lf][i]);   // logits tiny: no max needed
          p.s[i] = f2bf(e); cpl[lf] += e;
        }
        *(unsigned long long*)&Plds[l * 136 + wave * 32 + rf * 16 + g * 4] = p.ll;
      }
    }
    __syncthreads();
#pragma unroll
    for (int ks = 0; ks < 4; ++ks) {
      bf16x8 a;
#pragma unroll
      for (int j = 0; j < 8; ++j) a[j] = Vl[(ks * 32 + lk + j) * 68 + dloc];
#pragma unroll
      for (int lf = 0; lf < 4; lf++) {
        bf16x8 b = *(const bf16x8*)&Plds[(lf * 16 + lrow) * 136 + ks * 32 + lk];
        o2[lf] = __builtin_amdgcn_mfma_f32_16x16x32_bf16(a, b, o2[lf], 0, 0, 0);
      }
    }
  }
#pragma unroll
  for (int lf = 0; lf < 4; lf++) {
    float cp = cpl[lf];
    cp += __shfl_xor(cp, 16);
    cp += __shfl_xor(cp, 32);
    if (lane < 16)
      s3part[((bh * 8 + chunk) * 4 + wave) * LL + lf * 16 + lane] = cp;
    int l = lf * 16 + lrow;
#pragma unroll
    for (int i = 0; i < 4; i++) {
      int dd = wave * 16 + g * 4 + i;
      k3VTp[((size_t)chunk * BH + bh) * 4096 + dd * 64 + l] = o2[lf][i];
    }
  }
}

// ---------- per-(b,h): kernel2 softmax + MFMA Newton-Schulz (bf16 hi/lo) ----------
__global__ __launch_bounds__(512) void newton_inv(
    const float* __restrict__ QlmF, const float* __restrict__ KlmF,
    const float* __restrict__ k3VTp, const float* __restrict__ s3part,
    short* __restrict__ MTws) {
  __shared__ float Cf[64 * 68];
  __shared__ short BUF[12 * 4608];
  __shared__ float red[64];
  __shared__ float denom_s;
  short* Crm_h  = BUF + 0 * 4608;  short* Crm_l  = BUF + 1 * 4608;
  short* Vrm_h  = BUF + 2 * 4608;  short* Vrm_l  = BUF + 3 * 4608;
  short* Vcm_h  = BUF + 4 * 4608;  short* Vcm_l  = BUF + 5 * 4608;
  short* T1rm_h = BUF + 6 * 4608;  short* T1rm_l = BUF + 7 * 4608;
  short* T1cm_h = BUF + 8 * 4608;  short* T1cm_l = BUF + 9 * 4608;
  short* T2cm_h = BUF + 10 * 4608; short* T2cm_l = BUF + 11 * 4608;
  float* A_ = (float*)BUF;          // phase-1 alias (dead before BUF reuse)
  float* B_ = A_ + 64 * 68;

  const int bh = blockIdx.x, t = threadIdx.x;
  const int row = t >> 3, c0 = (t & 7) << 3;
  const int wv = t >> 6, lane = t & 63, lrow = lane & 15, g = lane >> 4;
  const int rw = (wv >> 1) * 16, cw = (wv & 1) * 32;

#pragma unroll
  for (int i = 0; i < 8; i++) {
    int e = t * 8 + i;
    A_[(e >> 6) * 68 + (e & 63)] = QlmF[bh * 4096 + e];
    B_[(e >> 6) * 68 + (e & 63)] = KlmF[bh * 4096 + e];
  }
  __syncthreads();
  {  // S2 = Qlm @ Klm^T ; row softmax -> Cf
    float4 ar[16];
#pragma unroll
    for (int q = 0; q < 16; q++) ar[q] = *(const float4*)&A_[row * 68 + q * 4];
    float o[8];
#pragma unroll
    for (int mm = 0; mm < 8; mm++) {
      const float4* br = (const float4*)&B_[(c0 + mm) * 68];
      float s = 0.f;
      for (int q = 0; q < 16; q++) {
        float4 b4 = br[q];
        s += ar[q].x * b4.x + ar[q].y * b4.y + ar[q].z * b4.z + ar[q].w * b4.w;
      }
      o[mm] = s;
    }
    float mx = o[0];
#pragma unroll
    for (int mm = 1; mm < 8; mm++) mx = fmaxf(mx, o[mm]);
    mx = fmaxf(mx, __shfl_xor(mx, 1));
    mx = fmaxf(mx, __shfl_xor(mx, 2));
    mx = fmaxf(mx, __shfl_xor(mx, 4));
    float ss = 0.f;
#pragma unroll
    for (int mm = 0; mm < 8; mm++) { o[mm] = expf(o[mm] - mx); ss += o[mm]; }
    ss += __shfl_xor(ss, 1); ss += __shfl_xor(ss, 2); ss += __shfl_xor(ss, 4);
    float r = 1.f / ss;
#pragma unroll
    for (int mm = 0; mm < 8; mm++) Cf[row * 68 + c0 + mm] = o[mm] * r;
  }
  __syncthreads();
  if (t < 64) {
    float s = 0.f;
    for (int l2 = 0; l2 < 64; l2++) s += Cf[l2 * 68 + t];
    red[t] = s;
  }
  __syncthreads();
  if (t == 0) {
    float m = red[0];
    for (int i = 1; i < 64; i++) m = fmaxf(m, red[i]);
    denom_s = m;
  }
  __syncthreads();
  {  // init: C hi/lo (rm); V0 = C^T/denom hi/lo (rm + cm)
    float rdn = 1.f / denom_s;
#pragma unroll
    for (int i = 0; i < 8; i++) {
      int e = t * 8 + i, r = e >> 6, c = e & 63;
      float cv = Cf[r * 68 + c];
      unsigned short chh = f2bf(cv);
      Crm_h[r * 72 + c] = (short)chh;
      Crm_l[r * 72 + c] = (short)f2bf(cv - bf2f(chh));
      float vv = Cf[c * 68 + r] * rdn;
      unsigned short vh = f2bf(vv);
      unsigned short vl = f2bf(vv - bf2f(vh));
      Vrm_h[r * 72 + c] = (short)vh; Vrm_l[r * 72 + c] = (short)vl;
      Vcm_h[c * 72 + r] = (short)vh; Vcm_l[c * 72 + r] = (short)vl;
    }
  }
  __syncthreads();

  f32x4 acc[2];
  auto mfmm = [&](const short* Xh, const short* Xl, const short* Yh, const short* Yl) {
    acc[0] = fzero4(); acc[1] = fzero4();
#pragma unroll
    for (int ks = 0; ks < 2; ++ks) {
      bf16x8 ah = *(const bf16x8*)&Xh[(rw + lrow) * 72 + ks * 32 + g * 8];
      bf16x8 al = *(const bf16x8*)&Xl[(rw + lrow) * 72 + ks * 32 + g * 8];
#pragma unroll
      for (int cf = 0; cf < 2; ++cf) {
        const int c = cw + cf * 16 + lrow;
        bf16x8 bhv = *(const bf16x8*)&Yh[c * 72 + ks * 32 + g * 8];
        bf16x8 blv = *(const bf16x8*)&Yl[c * 72 + ks * 32 + g * 8];
        acc[cf] = __builtin_amdgcn_mfma_f32_16x16x32_bf16(ah, bhv, acc[cf], 0, 0, 0);
        acc[cf] = __builtin_amdgcn_mfma_f32_16x16x32_bf16(ah, blv, acc[cf], 0, 0, 0);
        acc[cf] = __builtin_amdgcn_mfma_f32_16x16x32_bf16(al, bhv, acc[cf], 0, 0, 0);
      }
    }
  };
  auto storeRM = [&](short* H, short* Lo) {
#pragma unroll
    for (int cf = 0; cf < 2; ++cf)
#pragma unroll
      for (int i = 0; i < 4; ++i) {
        float z = acc[cf][i];
        unsigned short h = f2bf(z);
        int r = rw + g * 4 + i, c = cw + cf * 16 + lrow;
        H[r * 72 + c] = (short)h;
        Lo[r * 72 + c] = (short)f2bf(z - bf2f(h));
      }
  };
  auto storeCM = [&](short* H, short* Lo) {
#pragma unroll
    for (int cf = 0; cf < 2; ++cf) {
      U4 ph, pl;
#pragma unroll
      for (int i = 0; i < 4; ++i) {
        float z = acc[cf][i];
        unsigned short h = f2bf(z);
        ph.s[i] = h; pl.s[i] = f2bf(z - bf2f(h));
      }
      int c = cw + cf * 16 + lrow;
      *(unsigned long long*)&H[c * 72 + rw + g * 4] = ph.ll;
      *(unsigned long long*)&Lo[c * 72 + rw + g * 4] = pl.ll;
    }
  };

  float t1v[2][4];
  for (int it = 0; it < 6; ++it) {
    mfmm(Crm_h, Crm_l, Vcm_h, Vcm_l);          // T1 = C @ V
    __syncthreads();
    storeRM(T1rm_h, T1rm_l); storeCM(T1cm_h, T1cm_l);
    __syncthreads();
    mfmm(T1rm_h, T1rm_l, T1cm_h, T1cm_l);      // T1 @ T1
#pragma unroll
    for (int cf = 0; cf < 2; ++cf)
#pragma unroll
      for (int i = 0; i < 4; ++i) {
        int r = rw + g * 4 + i, c = cw + cf * 16 + lrow;
        t1v[cf][i] = bf2f((unsigned short)T1rm_h[r * 72 + c]) +
                     bf2f((unsigned short)T1rm_l[r * 72 + c]);
        acc[cf][i] = 7.f * t1v[cf][i] - acc[cf][i];
      }
    __syncthreads();
    storeCM(T2cm_h, T2cm_l);                   // T2 = 7*T1 - T1@T1
    __syncthreads();
    mfmm(T1rm_h, T1rm_l, T2cm_h, T2cm_l);      // T1 @ T2
#pragma unroll
    for (int cf = 0; cf < 2; ++cf)
#pragma unroll
      for (int i = 0; i < 4; ++i)
        acc[cf][i] = 15.f * t1v[cf][i] - acc[cf][i];
    __syncthreads();
    storeCM(T2cm_h, T2cm_l);                   // T3 overwrites T2 (post-barrier)
    __syncthreads();
    mfmm(Vrm_h, Vrm_l, T2cm_h, T2cm_l);        // V @ T3
#pragma unroll
    for (int cf = 0; cf < 2; ++cf)
#pragma unroll
      for (int i = 0; i < 4; ++i) {
        int r = rw + g * 4 + i, c = cw + cf * 16 + lrow;
        float v0 = bf2f((unsigned short)Vrm_h[r * 72 + c]) +
                   bf2f((unsigned short)Vrm_l[r * 72 + c]);
        acc[cf][i] = 0.25f * (13.f * v0 - acc[cf][i]);
      }
    __syncthreads();
    storeRM(Vrm_h, Vrm_l); storeCM(Vcm_h, Vcm_l);
    __syncthreads();
  }

  if (t < 64) {
    float s = 0.f;
    for (int i2 = 0; i2 < 32; i2++) s += s3part[(bh * 32 + i2) * LL + t];
    red[t] = 1.f / s;
  }
  __syncthreads();
#pragma unroll
  for (int i = 0; i < 8; i++) {
    int e = t * 8 + i, d = e >> 6, m = e & 63;
    float s = 0.f;
#pragma unroll
    for (int c = 0; c < 8; c++) s += k3VTp[((size_t)c * BH + bh) * 4096 + e];
    s *= red[m];
    unsigned short h = f2bf(s);
    T1rm_h[d * 72 + m] = (short)h;
    T1rm_l[d * 72 + m] = (short)f2bf(s - bf2f(h));
  }
  __syncthreads();
  mfmm(T1rm_h, T1rm_l, Vrm_h, Vrm_l);
#pragma unroll
  for (int cf = 0; cf < 2; ++cf)
#pragma unroll
    for (int i = 0; i < 4; ++i)
      MTws[bh * 4096 + (rw + g * 4 + i) * 64 + cw + cf * 16 + lrow] =
          (short)f2bf(acc[cf][i]);
}

// ---------- kernel1 softmax + @M  -> SV (in [B,N,C] bf16) ----------
__global__ __launch_bounds__(256) void pass2(
    const short* __restrict__ Qb, const short* __restrict__ Klmb,
    const short* __restrict__ MTws, short* __restrict__ SVb) {
  int bh = blockIdx.y, n0 = blockIdx.x * 128;
  int bb = bh / HH, hh = bh % HH;
  __shared__ short Klm[64 * 72];
  __shared__ short Mt[64 * 72];
  __shared__ short Pl[128 * 72];
  int t = threadIdx.x;
  for (int r = 0; r < 2; r++) {
    int e = t + r * 256;
    *(bf16x8*)&Klm[(e >> 3) * 72 + (e & 7) * 8] = *(const bf16x8*)&Klmb[bh * 4096 + e * 8];
    *(bf16x8*)&Mt[(e >> 3) * 72 + (e & 7) * 8]  = *(const bf16x8*)&MTws[bh * 4096 + e * 8];
  }
  __syncthreads();
  int wave = t >> 6, lane = t & 63, lrow = lane & 15, lk = (lane >> 4) << 3;
  int nw = wave * 32;
  bf16x8 aQ[2][2];
#pragma unroll
  for (int rf = 0; rf < 2; rf++)
#pragma unroll
    for (int ks = 0; ks < 2; ks++)
      aQ[rf][ks] = *(const bf16x8*)&Qb[((size_t)bh * NN + n0 + nw + rf * 16 + lrow) * DD + ks * 32 + lk];
  f32x4 s[2][4];
#pragma unroll
  for (int rf = 0; rf < 2; rf++)
#pragma unroll
    for (int jf = 0; jf < 4; jf++) s[rf][jf] = fzero4();
#pragma unroll
  for (int ks = 0; ks < 2; ks++) {
    bf16x8 bk[4];
#pragma unroll
    for (int jf = 0; jf < 4; jf++)
      bk[jf] = *(const bf16x8*)&Klm[(jf * 16 + lrow) * 72 + ks * 32 + lk];
#pragma unroll
    for (int rf = 0; rf < 2; rf++)
#pragma unroll
      for (int jf = 0; jf < 4; jf++)
        s[rf][jf] = __builtin_amdgcn_mfma_f32_16x16x32_bf16(aQ[rf][ks], bk[jf], s[rf][jf], 0, 0, 0);
  }
#pragma unroll
  for (int rf = 0; rf < 2; rf++)
#pragma unroll
    for (int i = 0; i < 4; i++) {
      float v0 = s[rf][0][i], v1 = s[rf][1][i], v2 = s[rf][2][i], v3 = s[rf][3][i];
      float mx = fmaxf(fmaxf(v0, v1), fmaxf(v2, v3));
      mx = fmaxf(mx, __shfl_xor(mx, 1));
      mx = fmaxf(mx, __shfl_xor(mx, 2));
      mx = fmaxf(mx, __shfl_xor(mx, 4));
      mx = fmaxf(mx, __shfl_xor(mx, 8));
      v0 = expf(v0 - mx); v1 = expf(v1 - mx); v2 = expf(v2 - mx); v3 = expf(v3 - mx);
      float ss = v0 + v1 + v2 + v3;
      ss += __shfl_xor(ss, 1); ss += __shfl_xor(ss, 2);
      ss += __shfl_xor(ss, 4); ss += __shfl_xor(ss, 8);
      float rr = 1.f / ss;
      int n = nw + rf * 16 + ((lane >> 4) << 2) + i;
      Pl[n * 72 + 0  + lrow] = (short)f2bf(v0 * rr);
      Pl[n * 72 + 16 + lrow] = (short)f2bf(v1 * rr);
      Pl[n * 72 + 32 + lrow] = (short)f2bf(v2 * rr);
      Pl[n * 72 + 48 + lrow] = (short)f2bf(v3 * rr);
    }
  __syncthreads();
  f32x4 o[2][4];
#pragma unroll
  for (int rf = 0; rf < 2; rf++)
#pragma unroll
    for (int df = 0; df < 4; df++) o[rf][df] = fzero4();
#pragma unroll
  for (int ks = 0; ks < 2; ks++) {
    bf16x8 aP[2];
#pragma unroll
    for (int rf = 0; rf < 2; rf++)
      aP[rf] = *(const bf16x8*)&Pl[(nw + rf * 16 + lrow) * 72 + ks * 32 + lk];
    bf16x8 bm[4];
#pragma unroll
    for (int df = 0; df < 4; df++)
      bm[df] = *(const bf16x8*)&Mt[(df * 16 + lrow) * 72 + ks * 32 + lk];
#pragma unroll
    for (int rf = 0; rf < 2; rf++)
#pragma unroll
      for (int df = 0; df < 4; df++)
        o[rf][df] = __builtin_amdgcn_mfma_f32_16x16x32_bf16(aP[rf], bm[df], o[rf][df], 0, 0, 0);
  }
#pragma unroll
  for (int rf = 0; rf < 2; rf++)
#pragma unroll
    for (int df = 0; df < 4; df++)
#pragma unroll
      for (int i = 0; i < 4; i++) {
        int n = n0 + nw + rf * 16 + ((lane >> 4) << 2) + i;
        SVb[((size_t)bb * NN + n) * CC + hh * 64 + df * 16 + lrow] = (short)f2bf(o[rf][df][i]);
      }
}

extern "C" void kernel_launch(void* const* d_in, const int* in_sizes, int n_in,
                              void* d_out, int out_size, void* d_ws, size_t ws_size,
                              hipStream_t stream) {
  const float* x      = (const float*)d_in[0];
  const float* w_qkv  = (const float*)d_in[1];
  const float* w_proj = (const float*)d_in[2];
  const float* b_proj = (const float*)d_in[3];
  float* out = (float*)d_out;

  char* p = (char*)d_ws;
  auto alloc = [&](size_t bytes) -> char* {
    char* r = p; p += (bytes + 255) & ~(size_t)255; return r;
  };
  short* xb     = (short*)alloc((size_t)MM_ * KQKV * 2);
  short* wqkvT  = (short*)alloc((size_t)NQKV * KQKV * 2);
  short* wprojT = (short*)alloc((size_t)CC * CC * 2);
  short* Qb     = (short*)alloc((size_t)BH * NN * DD * 2);
  short* Kb     = (short*)alloc((size_t)BH * NN * DD * 2);
  short* Vb     = (short*)alloc((size_t)BH * NN * DD * 2);
  short* Qlmb   = (short*)alloc((size_t)BH * LL * DD * 2);
  short* Klmb   = (short*)alloc((size_t)BH * LL * DD * 2);
  float* QlmF   = (float*)alloc((size_t)BH * LL * DD * 4);
  float* KlmF   = (float*)alloc((size_t)BH * LL * DD * 4);
  float* s3part = (float*)alloc((size_t)BH * 32 * LL * 4);
  float* k3VTp  = (float*)alloc((size_t)8 * BH * DD * LL * 4);
  short* MTws   = (short*)alloc((size_t)BH * DD * LL * 2);
  short* SVb    = (short*)alloc((size_t)MM_ * CC * 2);

  prep<<<26880, 256, 0, stream>>>(x, xb, w_qkv, wqkvT, w_proj, wprojT);
  gemm128<0><<<dim3((MM_ / 128) * (NQKV / 128)), 256, 0, stream>>>(
      xb, wqkvT, Qb, Kb, Vb, nullptr, nullptr, Qlmb, Klmb, QlmF, KlmF);
  e12<<<dim3(8, BH), 256, 0, stream>>>(Kb, Vb, Qlmb, k3VTp, s3part);
  newton_inv<<<BH, 512, 0, stream>>>(QlmF, KlmF, k3VTp, s3part, MTws);
  pass2<<<dim3(NN / 128, BH), 256, 0, stream>>>(Qb, Klmb, MTws, SVb);
  gemm128<1><<<dim3((MM_ / 128) * (CC / 128)), 256, 0, stream>>>(
      SVb, wprojT, nullptr, nullptr, Vb, b_proj, out,
      nullptr, nullptr, nullptr, nullptr);
}